// Round 15
// baseline (7985.681 us; speedup 1.0000x reference)
//
#include <hip/hip_runtime.h>
#include <math.h>

#define NB 16
#define NC 512
#define NH 16
#define NW 64
#define NT 128
#define NV 600
#define NE 80
#define EH 256
#define DH 512
#define NSEQ 256     // NB*NH
#define GEH 1024     // 4*EH
#define GDH 2048     // 4*DH

typedef float f32x4 __attribute__((ext_vector_type(4)));

// ---- workspace layout (float offsets) ----
#define OFF_XPRE_F 0ull          // 64*256*1024   (later aliased by embproj)
#define OFF_XPRE_B 16777216ull   // 64*256*1024   (later aliased by decoder scratch)
#define OFF_XT     33554432ull   // 64*256*512    (later aliased by wv_enc)
#define OFF_ENC    41943040ull   // 256*64*512
#define OFF_WENC   50331648ull   // 2*256*256*4
#define OFF_WDT    50855936ull   // 848*2048
#define OFF_WHT    52592640ull   // 512*512
#define OFF_WCT    52854784ull   // 1024*256
#define OFF_WOUTT  53116928ull   // 256*600
#define OFF_HA     53270528ull   // 2*256*256 (final encoder h)
#define OFF_CENC   53532672ull   // 2*256*256 (final encoder c)
#define OFF_CDEC   53663744ull   // 16*512  (cdec ping buffer A)
#define OFF_CTX0   53671936ull   // 16*512
#define OFF_OKT    53680128ull   // 768*16 (rows 0..255=O, 256..767=h)
#define WS_FLOATS  53708800ull   // ~214.8 MB

__device__ __forceinline__ float sigf(float x) {
  return __builtin_amdgcn_rcpf(1.f + __expf(-x));
}
__device__ __forceinline__ float tanhfast(float x) {
  float e = __expf(2.f * x);
  return 1.f - 2.f * __builtin_amdgcn_rcpf(e + 1.f);
}

// ---------- generic transpose ----------
__global__ void k_transpose(float* __restrict__ dst, const float* __restrict__ src,
                            int R, int Cc) {
  int idx = blockIdx.x * 256 + threadIdx.x;
  if (idx >= R * Cc) return;
  int c = idx / R, r = idx - c * R;
  dst[idx] = src[(size_t)r * Cc + c];
}

__global__ void k_prep_wenc(float* __restrict__ dst, const float* __restrict__ whh, int dir) {
  int idx = blockIdx.x * 256 + threadIdx.x;
  int g = idx & 3, j = (idx >> 2) & 255, k = idx >> 10;
  dst[(size_t)dir * 262144 + idx] = whh[((size_t)(g * 256 + j)) * 256 + k];
}

__global__ void k_buildXt(float* __restrict__ Xt, const float* __restrict__ feat) {
  __shared__ float tile[64][65];
  int n = blockIdx.x, cb = blockIdx.y * 64;
  int b = n >> 4, hh = n & 15;
  int tid = threadIdx.x;
  for (int i = 0; i < 16; ++i) {
    int c = (tid >> 6) + i * 4;
    int w = tid & 63;
    tile[c][w] = feat[(((size_t)b * NC + cb + c) * NH + hh) * NW + w];
  }
  __syncthreads();
  for (int i = 0; i < 16; ++i) {
    int w = (tid >> 6) + i * 4;
    int ci = tid & 63;
    Xt[((size_t)(w * NSEQ + n)) * NC + cb + ci] = tile[ci][w];
  }
}

// ---------- fp32 GEMM ----------
__global__ __launch_bounds__(256) void k_gemm_nt(
    const float* __restrict__ A, const float* __restrict__ Wt,
    const float* __restrict__ bias1, const float* __restrict__ bias2,
    float* __restrict__ Cout, int M, int Nn, int K) {
  __shared__ float As[128 * 32];
  __shared__ float Bs[128 * 32];
  int tid = threadIdx.x;
  int mb = blockIdx.x * 128, nb = blockIdx.y * 128;
  int tx = tid & 15, ty = tid >> 4;
  int row0 = ty * 8, col0 = tx * 8;
  float acc[8][8];
#pragma unroll
  for (int i = 0; i < 8; ++i)
#pragma unroll
    for (int j = 0; j < 8; ++j) acc[i][j] = 0.f;
  int lm = tid >> 1, lk = (tid & 1) * 8;
  int sw = 4 * ((lm >> 3) & 7);
  int p0 = (lk + sw) & 31, p1 = (lk + 4 + sw) & 31;
  const float* Ap = A + (size_t)(mb + lm) * K + lk;
  const float* Bp = Wt + (size_t)(nb + lm) * K + lk;
  for (int k0 = 0; k0 < K; k0 += 16) {
    float4 a0 = *(const float4*)(Ap + k0);
    float4 a1 = *(const float4*)(Ap + k0 + 4);
    float4 b0 = *(const float4*)(Bp + k0);
    float4 b1 = *(const float4*)(Bp + k0 + 4);
    __syncthreads();
    *(float4*)&As[lm * 32 + p0] = a0;
    *(float4*)&As[lm * 32 + p1] = a1;
    *(float4*)&Bs[lm * 32 + p0] = b0;
    *(float4*)&Bs[lm * 32 + p1] = b1;
    __syncthreads();
#pragma unroll
    for (int kq = 0; kq < 4; ++kq) {
      float4 av[8], bv[8];
#pragma unroll
      for (int i = 0; i < 8; ++i) {
        int m = row0 + i;
        av[i] = *(float4*)&As[m * 32 + ((kq * 4 + 4 * ((m >> 3) & 7)) & 31)];
      }
#pragma unroll
      for (int j = 0; j < 8; ++j) {
        int n = col0 + j;
        bv[j] = *(float4*)&Bs[n * 32 + ((kq * 4 + 4 * ((n >> 3) & 7)) & 31)];
      }
#pragma unroll
      for (int i = 0; i < 8; ++i)
#pragma unroll
        for (int j = 0; j < 8; ++j)
          acc[i][j] += av[i].x * bv[j].x + av[i].y * bv[j].y
                     + av[i].z * bv[j].z + av[i].w * bv[j].w;
    }
  }
  float bs[8];
#pragma unroll
  for (int j = 0; j < 8; ++j) {
    float v = bias1 ? bias1[nb + col0 + j] : 0.f;
    if (bias2) v += bias2[nb + col0 + j];
    bs[j] = v;
  }
  for (int i = 0; i < 8; ++i) {
    float* cp = Cout + (size_t)(mb + row0 + i) * Nn + nb + col0;
#pragma unroll
    for (int j = 0; j < 8; ++j) cp[j] = acc[i][j] + bs[j];
  }
}

// ---------- seq-partitioned encoder: 4-way k-split, 1024 threads ----------
__global__ __launch_bounds__(1024) void k_encoder_s(
    const float* __restrict__ wenc, const float* __restrict__ xpreF,
    const float* __restrict__ xpreB, const float* __restrict__ Vh0,
    const float* __restrict__ Vc0, float* __restrict__ encout,
    float* __restrict__ hT_out, float* __restrict__ cT_out) {
  __shared__ float hs[4][256];          // 4 KB
  __shared__ float pacc[3][16][256];    // 48 KB partials from kq=1..3
  int bid = blockIdx.x;
  int dir = bid >> 6;
  int s0 = (bid & 63) * 4;
  int tid = threadIdx.x;
  int j = tid & 255, kq = tid >> 8;
  float c[4];
  if (kq == 0) {
    float h0 = Vh0[dir * 256 + j];
    float c0v = Vc0[dir * 256 + j];
#pragma unroll
    for (int s = 0; s < 4; ++s) { hs[s][j] = h0; c[s] = c0v; }
  }
  __syncthreads();
  const float* wp = wenc + (size_t)dir * 262144 + (size_t)(kq * 64) * 1024 + (size_t)j * 4;
  const float* xbase = dir ? xpreB : xpreF;
  for (int t = 0; t < 64; ++t) {
    int w = dir ? (63 - t) : t;
    float acc[4][4];
#pragma unroll
    for (int s = 0; s < 4; ++s)
#pragma unroll
      for (int g = 0; g < 4; ++g) acc[s][g] = 0.f;
#pragma unroll 8
    for (int k = 0; k < 64; ++k) {
      float4 w4 = *(const float4*)(wp + (size_t)k * 1024);
      int kk = kq * 64 + k;
      float h0k = hs[0][kk], h1k = hs[1][kk], h2k = hs[2][kk], h3k = hs[3][kk];
      acc[0][0] += w4.x * h0k; acc[0][1] += w4.y * h0k; acc[0][2] += w4.z * h0k; acc[0][3] += w4.w * h0k;
      acc[1][0] += w4.x * h1k; acc[1][1] += w4.y * h1k; acc[1][2] += w4.z * h1k; acc[1][3] += w4.w * h1k;
      acc[2][0] += w4.x * h2k; acc[2][1] += w4.y * h2k; acc[2][2] += w4.z * h2k; acc[2][3] += w4.w * h2k;
      acc[3][0] += w4.x * h3k; acc[3][1] += w4.y * h3k; acc[3][2] += w4.z * h3k; acc[3][3] += w4.w * h3k;
    }
    if (kq > 0) {
#pragma unroll
      for (int s = 0; s < 4; ++s)
#pragma unroll
        for (int g = 0; g < 4; ++g)
          pacc[kq - 1][s * 4 + g][j] = acc[s][g];
    }
    __syncthreads();
    if (kq == 0) {
#pragma unroll
      for (int s = 0; s < 4; ++s) {
        int n = s0 + s;
        const float* xp = xbase + ((size_t)w * NSEQ + n) * GEH;
        float g4[4];
#pragma unroll
        for (int g = 0; g < 4; ++g)
          g4[g] = acc[s][g] + pacc[0][s * 4 + g][j] + pacc[1][s * 4 + g][j]
                + pacc[2][s * 4 + g][j] + xp[g * 256 + j];
        float cn = sigf(g4[1]) * c[s] + sigf(g4[0]) * tanhfast(g4[2]);
        c[s] = cn;
        float hn = sigf(g4[3]) * tanhfast(cn);
        hs[s][j] = hn;
        encout[((size_t)n * NW + w) * (2 * EH) + dir * EH + j] = hn;
      }
    }
    __syncthreads();
  }
  if (kq == 0) {
#pragma unroll
    for (int s = 0; s < 4; ++s) {
      int n = s0 + s;
      hT_out[((size_t)(dir * NSEQ + n)) * EH + j] = hs[s][j];
      cT_out[((size_t)(dir * NSEQ + n)) * EH + j] = c[s];
    }
  }
}

__global__ void k_conv(const float* __restrict__ hA, const float* __restrict__ cE,
                       const float* __restrict__ enc, float* __restrict__ cdec,
                       float* __restrict__ okT, float* __restrict__ ctx0) {
  int b = blockIdx.x, tid = threadIdx.x;
  for (int d = tid; d < 512; d += 256) {
    float s = 0.f;
    for (int p = 0; p < 1024; ++p) s += enc[((size_t)b * 1024 + p) * 512 + d];
    ctx0[(size_t)b * 512 + d] = s * (1.f / 1024.f);
    int dir = d >> 8, u = d & 255;
    float sh = 0.f, sc_ = 0.f;
    for (int hh = 0; hh < 16; ++hh) {
      size_t idx = ((size_t)(dir * NSEQ + b * 16 + hh)) * EH + u;
      sh += hA[idx]; sc_ += cE[idx];
    }
    cdec[(size_t)b * 512 + d] = sc_ * (1.f / 16.f);
    okT[(size_t)(256 + d) * 16 + b] = sh * (1.f / 16.f);
  }
}

// ---------- O0 + lin_h(h0) ----------
__global__ void k_O0v2(const float* __restrict__ okT, const float* __restrict__ ctx0,
                       const float* __restrict__ wcT, const float* __restrict__ wcb,
                       const float* __restrict__ whT, const float* __restrict__ whb,
                       float* __restrict__ okT_o, float* __restrict__ linh) {
  int b = blockIdx.x, tid = threadIdx.x;
  float a = wcb[tid];
  for (int k = 0; k < 512; ++k)
    a += okT[(size_t)(256 + k) * 16 + b] * wcT[(size_t)k * 256 + tid];
  const float* cb = ctx0 + (size_t)b * 512;
  for (int k = 0; k < 512; ++k)
    a += cb[k] * wcT[(size_t)(512 + k) * 256 + tid];
  okT_o[(size_t)tid * 16 + b] = tanhfast(a);
  for (int d = tid; d < 512; d += 256) {
    float v = whb[d];
    for (int k = 0; k < 512; ++k)
      v += okT[(size_t)(256 + k) * 16 + b] * whT[(size_t)k * 512 + d];
    linh[(size_t)b * 512 + d] = v;
  }
}

// ---------- embedding projection, tiled: block = 256 g x 32 tb ----------
__global__ __launch_bounds__(256) void k_embproj(
    const int* __restrict__ formulas, const float* __restrict__ emb,
    const float* __restrict__ wdT, const float* __restrict__ b1,
    const float* __restrict__ b2, float* __restrict__ ep) {
  __shared__ float se[32][NE];
  int gc = blockIdx.x, tc = blockIdx.y;
  int tid = threadIdx.x;
  int g = gc * 256 + tid;
  // stage 32 embedding vectors
  for (int i = tid; i < 32 * NE; i += 256) {
    int ti = i / NE, k = i - ti * NE;
    int tb = tc * 32 + ti;
    int b = tb & 15, t = tb >> 4;
    int tok = formulas[b * NT + t];
    se[ti][k] = emb[(size_t)tok * NE + k];
  }
  __syncthreads();
  float acc[32];
  float bias = b1[g] + b2[g];
#pragma unroll
  for (int i = 0; i < 32; ++i) acc[i] = bias;
  for (int k = 0; k < NE; ++k) {
    float w = wdT[(size_t)k * GDH + g];
#pragma unroll
    for (int i = 0; i < 32; ++i) acc[i] += se[i][k] * w;
  }
#pragma unroll
  for (int i = 0; i < 32; ++i)
    ep[(size_t)(tc * 32 + i) * GDH + g] = acc[i];
}

// ---------- logits helper (exp + per-chunk sums) ----------
__device__ __forceinline__ void logits_block(
    int vc, int lane, int wq, const float* __restrict__ okT,
    const float* __restrict__ woutT, const float* __restrict__ woutb,
    float* __restrict__ ev, float* __restrict__ evp) {
  int v = vc * 64 + lane;
  bool valid = v < NV;
  int vl = valid ? v : (NV - 1);
  float acc[4] = {0.f, 0.f, 0.f, 0.f};
  for (int k = 0; k < 256; ++k) {
    float w = woutT[(size_t)k * NV + vl];
    float4 o4 = *(const float4*)&okT[(size_t)k * 16 + wq * 4];
    acc[0] += w * o4.x; acc[1] += w * o4.y; acc[2] += w * o4.z; acc[3] += w * o4.w;
  }
  float bs = woutb[vl];
#pragma unroll
  for (int i = 0; i < 4; ++i) {
    float e = valid ? __expf(acc[i] + bs) : 0.f;
    if (valid) ev[(size_t)(wq * 4 + i) * NV + v] = e;
    float s = e;
#pragma unroll
    for (int m = 1; m < 64; m <<= 1) s += __shfl_xor(s, m, 64);
    if (lane == 0) evp[(wq * 4 + i) * 16 + vc] = s;
  }
}

__device__ __forceinline__ void norm_block(
    int b, int tid, const float* __restrict__ ev, const float* __restrict__ evp,
    float* __restrict__ outp, int t) {
  float tot = 0.f;
#pragma unroll
  for (int i = 0; i < 10; ++i) tot += evp[b * 16 + i];
  float r = __builtin_amdgcn_rcpf(tot);
  float* orow = outp + ((size_t)b * NT + t) * NV;
  orow[tid] = ev[b * NV + tid] * r;
  orow[tid + 256] = ev[b * NV + tid + 256] * r;
  if (tid < 88) orow[tid + 512] = ev[b * NV + tid + 512] * r;
}

// ---------- decoder K1: fused attention (1024) | gates (48) | logits (10) ----------
__global__ __launch_bounds__(256) void k_dec1(
    const float* __restrict__ okT, const float* __restrict__ wdT,
    const float* __restrict__ woutT, const float* __restrict__ woutb,
    const float* __restrict__ linh, const float* __restrict__ beta,
    const float* __restrict__ wvenc, const float* __restrict__ enc,
    float* __restrict__ gpart, float* __restrict__ ctxp,
    float* __restrict__ spart, float* __restrict__ ev, float* __restrict__ evp,
    int t) {
  __shared__ float sscore[16];
  __shared__ float cpart[4][512];
  int bid = blockIdx.x, tid = threadIdx.x;
  int lane = tid & 63, wq = tid >> 6;

  if (bid < 1024) {
    // attention tile: b = bid>>6, pc = bid&63 (16 positions); 4 waves x 4 pos
    int b = bid >> 6, pc = bid & 63;
    int d0 = lane * 8;
    float lh[8], bt[8];
    const float* lp = linh + (size_t)b * 512 + d0;
#pragma unroll
    for (int jj = 0; jj < 8; ++jj) { lh[jj] = lp[jj]; bt[jj] = beta[d0 + jj]; }
    float c8[8] = {0.f, 0.f, 0.f, 0.f, 0.f, 0.f, 0.f, 0.f};
#pragma unroll
    for (int pi = 0; pi < 4; ++pi) {
      int p = pc * 16 + wq * 4 + pi;
      const float* wvp = wvenc + ((size_t)(b * 1024 + p)) * 512 + d0;
      const float* erp = enc + ((size_t)(b * 1024 + p)) * 512 + d0;
      f32x4 wv0 = __builtin_nontemporal_load((const f32x4*)wvp);
      f32x4 wv1 = __builtin_nontemporal_load((const f32x4*)(wvp + 4));
      f32x4 e0 = __builtin_nontemporal_load((const f32x4*)erp);
      f32x4 e1 = __builtin_nontemporal_load((const f32x4*)(erp + 4));
      float e = bt[0] * tanhfast(lh[0] + wv0.x) + bt[1] * tanhfast(lh[1] + wv0.y)
              + bt[2] * tanhfast(lh[2] + wv0.z) + bt[3] * tanhfast(lh[3] + wv0.w)
              + bt[4] * tanhfast(lh[4] + wv1.x) + bt[5] * tanhfast(lh[5] + wv1.y)
              + bt[6] * tanhfast(lh[6] + wv1.z) + bt[7] * tanhfast(lh[7] + wv1.w);
#pragma unroll
      for (int m = 1; m < 64; m <<= 1) e += __shfl_xor(e, m, 64);
      float s = __expf(e);   // |e|<=5.2, safe without max-sub
      if (lane == 0) sscore[wq * 4 + pi] = s;
      c8[0] += s * e0.x; c8[1] += s * e0.y; c8[2] += s * e0.z; c8[3] += s * e0.w;
      c8[4] += s * e1.x; c8[5] += s * e1.y; c8[6] += s * e1.z; c8[7] += s * e1.w;
    }
#pragma unroll
    for (int jj = 0; jj < 8; ++jj) cpart[wq][d0 + jj] = c8[jj];
    __syncthreads();
    {
      int d = tid * 2;
      float r0 = cpart[0][d] + cpart[1][d] + cpart[2][d] + cpart[3][d];
      float r1 = cpart[0][d + 1] + cpart[1][d + 1] + cpart[2][d + 1] + cpart[3][d + 1];
      *(float2*)&ctxp[((size_t)(b * 64 + pc)) * 512 + d] = make_float2(r0, r1);
    }
    if (tid == 0) {
      float s = 0.f;
#pragma unroll
      for (int p = 0; p < 16; ++p) s += sscore[p];
      spart[b * 64 + pc] = s;
    }
  } else if (bid < 1072) {
    // gates: oc = idx/6 (8 o-chunks of 256), kc = idx%6 (6 k-chunks of 128)
    int idx = bid - 1024;
    int oc = idx / 6, kc = idx - oc * 6;
    int o = oc * 256 + tid, k0 = kc * 128;
    const float* wp = wdT + (size_t)(80 + k0) * GDH + o;
    const float* sp = okT + (size_t)k0 * 16;
    float acc[16];
#pragma unroll
    for (int i = 0; i < 16; ++i) acc[i] = 0.f;
    for (int kk = 0; kk < 128; ++kk) {
      float w = wp[(size_t)kk * GDH];
#pragma unroll
      for (int bb = 0; bb < 16; ++bb) acc[bb] += sp[kk * 16 + bb] * w;
    }
#pragma unroll
    for (int bb = 0; bb < 16; ++bb)
      gpart[((size_t)(kc * 16 + bb)) * GDH + o] = acc[bb];
  } else {
    if (t > 0) logits_block(bid - 1072, lane, wq, okT, woutT, woutb, ev, evp);
  }
}

// ---------- decoder K2: reduce+cell+O_t+lin_h (64 blocks) | norm (16) ----------
__global__ __launch_bounds__(256) void k_dec2(
    const float* __restrict__ gpart, const float* __restrict__ ep,
    const float* __restrict__ ctxp, const float* __restrict__ spart,
    const float* __restrict__ wcT, const float* __restrict__ wcb,
    const float* __restrict__ whT, const float* __restrict__ whb,
    const float* __restrict__ ev, const float* __restrict__ evp,
    float* __restrict__ cdecA, float* __restrict__ cdecB,
    float* __restrict__ okT, float* __restrict__ linh,
    float* __restrict__ outp, int t) {
  __shared__ float smem[1280];
  int bid = blockIdx.x, tid = threadIdx.x;
  if (bid < 64) {
    int b = bid >> 2, q = bid & 3;
    const float* cold = (t & 1) ? cdecB : cdecA;
    float* cnew = (t & 1) ? cdecA : cdecB;
    float Ssum = 0.f;
#pragma unroll
    for (int pc = 0; pc < 64; ++pc) Ssum += spart[b * 64 + pc];
    float rS = __builtin_amdgcn_rcpf(Ssum);
    {
      int d = tid * 2;
      float s0 = 0.f, s1 = 0.f;
#pragma unroll 8
      for (int pc = 0; pc < 64; ++pc) {
        float2 c2 = *(const float2*)&ctxp[((size_t)(b * 64 + pc)) * 512 + d];
        s0 += c2.x; s1 += c2.y;
      }
      smem[512 + d] = s0 * rS;
      smem[512 + d + 1] = s1 * rS;
    }
#pragma unroll
    for (int half = 0; half < 2; ++half) {
      int j = half * 256 + tid;
      float g4[4];
#pragma unroll
      for (int gi = 0; gi < 4; ++gi) {
        float v = ep[((size_t)(t * 16 + b)) * GDH + gi * 512 + j];
#pragma unroll
        for (int kc = 0; kc < 6; ++kc)
          v += gpart[((size_t)(kc * 16 + b)) * GDH + gi * 512 + j];
        g4[gi] = v;
      }
      size_t ci = (size_t)b * 512 + j;
      float cn = sigf(g4[1]) * cold[ci] + sigf(g4[0]) * tanhfast(g4[2]);
      cnew[ci] = cn;
      float hn = sigf(g4[3]) * tanhfast(cn);
      smem[j] = hn;
      okT[(size_t)(256 + j) * 16 + b] = hn;
    }
    __syncthreads();
    // O_t slice: outputs q*64 .. q*64+63, k over [h;ctx]=smem[0..1023]
    {
      int ol = tid & 63, kq = tid >> 6;
      int o = q * 64 + ol;
      float a = 0.f;
      const float* wp = wcT + (size_t)(kq * 256) * 256 + o;
      const float* sp = smem + kq * 256;
      for (int k = 0; k < 256; ++k) a += wp[(size_t)k * 256] * sp[k];
      smem[1024 + kq * 64 + ol] = a;
    }
    __syncthreads();
    if (tid < 64) {
      float s = smem[1024 + tid] + smem[1088 + tid] + smem[1152 + tid] + smem[1216 + tid];
      int o = q * 64 + tid;
      okT[(size_t)o * 16 + b] = tanhfast(s + wcb[o]);
    }
    __syncthreads();
    // lin_h slice: outputs q*128 .. q*128+127, k over h=smem[0..511]
    {
      int o2 = tid & 127, kh = tid >> 7;
      int o = q * 128 + o2;
      float a = 0.f;
      const float* wp = whT + (size_t)(kh * 256) * 512 + o;
      const float* sp = smem + kh * 256;
      for (int k = 0; k < 256; ++k) a += wp[(size_t)k * 512] * sp[k];
      smem[1024 + kh * 128 + o2] = a;
    }
    __syncthreads();
    if (tid < 128) {
      int o = q * 128 + tid;
      float s = smem[1024 + tid] + smem[1152 + tid];
      linh[(size_t)b * 512 + o] = s + whb[o];
    }
  } else {
    if (t > 0) norm_block(bid - 64, tid, ev, evp, outp, t - 1);
  }
}

// ---------- tail: logits for t=127 ----------
__global__ __launch_bounds__(256) void k_log_tail(
    const float* __restrict__ okT, const float* __restrict__ woutT,
    const float* __restrict__ woutb, float* __restrict__ ev, float* __restrict__ evp) {
  int lane = threadIdx.x & 63, wq = threadIdx.x >> 6;
  logits_block(blockIdx.x, lane, wq, okT, woutT, woutb, ev, evp);
}

__global__ void k_norm(const float* __restrict__ ev, const float* __restrict__ evp,
                       float* __restrict__ outp, int t) {
  norm_block(blockIdx.x, threadIdx.x, ev, evp, outp, t);
}

__global__ void k_argmax(const float* __restrict__ outp, float* __restrict__ tgt) {
  int bt = blockIdx.x;
  int lane = threadIdx.x;
  const float* row = outp + (size_t)bt * NV;
  float bv = -1.f;
  int bi = 0;
  for (int v = lane; v < NV; v += 64) {
    float x = row[v];
    if (x > bv) { bv = x; bi = v; }
  }
#pragma unroll
  for (int m = 1; m < 64; m <<= 1) {
    float ov = __shfl_xor(bv, m, 64);
    int oi = __shfl_xor(bi, m, 64);
    if (ov > bv || (ov == bv && oi < bi)) { bv = ov; bi = oi; }
  }
  if (lane == 0) tgt[bt] = (float)bi;
}

extern "C" void kernel_launch(void* const* d_in, const int* in_sizes, int n_in,
                              void* d_out, int out_size, void* d_ws, size_t ws_size,
                              hipStream_t stream) {
  (void)in_sizes; (void)n_in; (void)out_size;
  if (ws_size < WS_FLOATS * sizeof(float)) return;

  const float* feat     = (const float*)d_in[0];
  const int*   formulas = (const int*)d_in[1];
  const float* Wih_f    = (const float*)d_in[2];
  const float* Whh_f    = (const float*)d_in[3];
  const float* bih_f    = (const float*)d_in[4];
  const float* bhh_f    = (const float*)d_in[5];
  const float* Wih_b    = (const float*)d_in[6];
  const float* Whh_b    = (const float*)d_in[7];
  const float* bih_b    = (const float*)d_in[8];
  const float* bhh_b    = (const float*)d_in[9];
  const float* emb      = (const float*)d_in[10];
  const float* Wc_w     = (const float*)d_in[11];
  const float* Wc_b     = (const float*)d_in[12];
  const float* Wout_w   = (const float*)d_in[13];
  const float* Wout_b   = (const float*)d_in[14];
  const float* Vh0      = (const float*)d_in[15];
  const float* Vc0      = (const float*)d_in[16];
  const float* beta     = (const float*)d_in[17];
  const float* Wh_w     = (const float*)d_in[18];
  const float* Wh_b     = (const float*)d_in[19];
  const float* Wv_w     = (const float*)d_in[20];
  const float* Wv_b     = (const float*)d_in[21];
  const float* Wdec_ih  = (const float*)d_in[22];
  const float* Wdec_hh  = (const float*)d_in[23];
  const float* bdec_ih  = (const float*)d_in[24];
  const float* bdec_hh  = (const float*)d_in[25];

  float* ws = (float*)d_ws;
  float* xpreF  = ws + OFF_XPRE_F;
  float* xpreB  = ws + OFF_XPRE_B;
  float* xt     = ws + OFF_XT;
  float* encout = ws + OFF_ENC;
  float* wenc   = ws + OFF_WENC;
  float* wdT    = ws + OFF_WDT;
  float* whT    = ws + OFF_WHT;
  float* wcT    = ws + OFF_WCT;
  float* woutT  = ws + OFF_WOUTT;
  float* hA     = ws + OFF_HA;
  float* cenc   = ws + OFF_CENC;
  float* cdecA  = ws + OFF_CDEC;
  float* ctx0   = ws + OFF_CTX0;
  float* okT    = ws + OFF_OKT;
  // decoder scratch aliased into xpreB (free after encoder)
  float* gpart  = xpreB;                 // 6*16*2048 = 196608
  float* ctxp   = gpart + 196608;        // 16*64*512 = 524288
  float* spart  = ctxp + 524288;         // 1024
  float* ev     = spart + 1024;          // 16*600 = 9600
  float* evp    = ev + 9600;             // 256
  float* linh   = evp + 256;             // 16*512 = 8192
  float* cdecB  = linh + 8192;           // 8192
  float* embproj = xpreF;                // alias (free after encoder)
  float* wvenc   = xt;                   // alias (free after input GEMMs)

  float* out_logits = (float*)d_out;
  float* out_tgt    = out_logits + (size_t)NB * NT * NV;

  // ---- prep ----
  k_transpose<<<(2048 * 336 + 255) / 256, 256, 0, stream>>>(wdT, Wdec_ih, 2048, 336);
  k_transpose<<<(2048 * 512 + 255) / 256, 256, 0, stream>>>(wdT + 336 * 2048, Wdec_hh, 2048, 512);
  k_transpose<<<(512 * 512 + 255) / 256, 256, 0, stream>>>(whT, Wh_w, 512, 512);
  k_transpose<<<(256 * 1024 + 255) / 256, 256, 0, stream>>>(wcT, Wc_w, 256, 1024);
  k_transpose<<<(600 * 256 + 255) / 256, 256, 0, stream>>>(woutT, Wout_w, 600, 256);
  k_prep_wenc<<<1024, 256, 0, stream>>>(wenc, Whh_f, 0);
  k_prep_wenc<<<1024, 256, 0, stream>>>(wenc, Whh_b, 1);
  k_buildXt<<<dim3(256, 8), 256, 0, stream>>>(xt, feat);
  k_gemm_nt<<<dim3(128, 8), 256, 0, stream>>>(xt, Wih_f, bih_f, bhh_f, xpreF, 16384, 1024, 512);
  k_gemm_nt<<<dim3(128, 8), 256, 0, stream>>>(xt, Wih_b, bih_b, bhh_b, xpreB, 16384, 1024, 512);

  // ---- encoder: one dispatch, zero grid sync ----
  k_encoder_s<<<128, 1024, 0, stream>>>(wenc, xpreF, xpreB, Vh0, Vc0, encout, hA, cenc);

  k_gemm_nt<<<dim3(128, 4), 256, 0, stream>>>(encout, Wv_w, Wv_b, nullptr, wvenc, 16384, 512, 512);
  k_conv<<<16, 256, 0, stream>>>(hA, cenc, encout, cdecA, okT, ctx0);
  k_O0v2<<<16, 256, 0, stream>>>(okT, ctx0, wcT, Wc_b, whT, Wh_b, okT, linh);
  k_embproj<<<dim3(8, 64), 256, 0, stream>>>(formulas, emb, wdT, bdec_ih, bdec_hh, embproj);

  // ---- decoder: 2 dispatches per step ----
  for (int t = 0; t < NT; ++t) {
    k_dec1<<<1082, 256, 0, stream>>>(okT, wdT, woutT, Wout_b, linh, beta, wvenc, encout,
                                     gpart, ctxp, spart, ev, evp, t);
    k_dec2<<<80, 256, 0, stream>>>(gpart, embproj, ctxp, spart, wcT, Wc_b, whT, Wh_b,
                                   ev, evp, cdecA, cdecB, okT, linh, out_logits, t);
  }
  // ---- tail ----
  k_log_tail<<<10, 256, 0, stream>>>(okT, woutT, Wout_b, ev, evp);
  k_norm<<<16, 256, 0, stream>>>(ev, evp, out_logits, NT - 1);
  k_argmax<<<NB * NT, 64, 0, stream>>>(out_logits, out_tgt);
}

// Round 16
// 7245.808 us; speedup vs baseline: 1.1021x; 1.1021x over previous
//
#include <hip/hip_runtime.h>
#include <math.h>

#define NB 16
#define NC 512
#define NH 16
#define NW 64
#define NT 128
#define NV 600
#define NE 80
#define EH 256
#define DH 512
#define NSEQ 256     // NB*NH
#define GEH 1024     // 4*EH
#define GDH 2048     // 4*DH

typedef float f32x4 __attribute__((ext_vector_type(4)));

// ---- workspace layout (float offsets) ----
#define OFF_XPRE_F 0ull          // 64*256*1024   (later aliased by embproj)
#define OFF_XPRE_B 16777216ull   // 64*256*1024   (later aliased by decoder scratch)
#define OFF_XT     33554432ull   // 64*256*512    (later aliased by wv_enc)
#define OFF_ENC    41943040ull   // 256*64*512
#define OFF_WENC   50331648ull   // 2*256*256*4
#define OFF_WDT    50855936ull   // 848*2048
#define OFF_WHT    52592640ull   // 512*512
#define OFF_WCT    52854784ull   // 1024*256
#define OFF_WOUTT  53116928ull   // 256*600
#define OFF_HA     53270528ull   // 2*256*256 (final encoder h)
#define OFF_CENC   53532672ull   // 2*256*256 (final encoder c)
#define OFF_CDEC   53663744ull   // 16*512  (cdec ping buffer A)
#define OFF_CTX0   53671936ull   // 16*512
#define OFF_OKT    53680128ull   // 768*16 (rows 0..255=O, 256..767=h)
#define WS_FLOATS  53708800ull   // ~214.8 MB

__device__ __forceinline__ float sigf(float x) {
  return __builtin_amdgcn_rcpf(1.f + __expf(-x));
}
__device__ __forceinline__ float tanhfast(float x) {
  float e = __expf(2.f * x);
  return 1.f - 2.f * __builtin_amdgcn_rcpf(e + 1.f);
}

// ---------- generic transpose ----------
__global__ void k_transpose(float* __restrict__ dst, const float* __restrict__ src,
                            int R, int Cc) {
  int idx = blockIdx.x * 256 + threadIdx.x;
  if (idx >= R * Cc) return;
  int c = idx / R, r = idx - c * R;
  dst[idx] = src[(size_t)r * Cc + c];
}

__global__ void k_prep_wenc(float* __restrict__ dst, const float* __restrict__ whh, int dir) {
  int idx = blockIdx.x * 256 + threadIdx.x;
  int g = idx & 3, j = (idx >> 2) & 255, k = idx >> 10;
  dst[(size_t)dir * 262144 + idx] = whh[((size_t)(g * 256 + j)) * 256 + k];
}

__global__ void k_buildXt(float* __restrict__ Xt, const float* __restrict__ feat) {
  __shared__ float tile[64][65];
  int n = blockIdx.x, cb = blockIdx.y * 64;
  int b = n >> 4, hh = n & 15;
  int tid = threadIdx.x;
  for (int i = 0; i < 16; ++i) {
    int c = (tid >> 6) + i * 4;
    int w = tid & 63;
    tile[c][w] = feat[(((size_t)b * NC + cb + c) * NH + hh) * NW + w];
  }
  __syncthreads();
  for (int i = 0; i < 16; ++i) {
    int w = (tid >> 6) + i * 4;
    int ci = tid & 63;
    Xt[((size_t)(w * NSEQ + n)) * NC + cb + ci] = tile[ci][w];
  }
}

// ---------- fp32 GEMM ----------
__global__ __launch_bounds__(256) void k_gemm_nt(
    const float* __restrict__ A, const float* __restrict__ Wt,
    const float* __restrict__ bias1, const float* __restrict__ bias2,
    float* __restrict__ Cout, int M, int Nn, int K) {
  __shared__ float As[128 * 32];
  __shared__ float Bs[128 * 32];
  int tid = threadIdx.x;
  int mb = blockIdx.x * 128, nb = blockIdx.y * 128;
  int tx = tid & 15, ty = tid >> 4;
  int row0 = ty * 8, col0 = tx * 8;
  float acc[8][8];
#pragma unroll
  for (int i = 0; i < 8; ++i)
#pragma unroll
    for (int j = 0; j < 8; ++j) acc[i][j] = 0.f;
  int lm = tid >> 1, lk = (tid & 1) * 8;
  int sw = 4 * ((lm >> 3) & 7);
  int p0 = (lk + sw) & 31, p1 = (lk + 4 + sw) & 31;
  const float* Ap = A + (size_t)(mb + lm) * K + lk;
  const float* Bp = Wt + (size_t)(nb + lm) * K + lk;
  for (int k0 = 0; k0 < K; k0 += 16) {
    float4 a0 = *(const float4*)(Ap + k0);
    float4 a1 = *(const float4*)(Ap + k0 + 4);
    float4 b0 = *(const float4*)(Bp + k0);
    float4 b1 = *(const float4*)(Bp + k0 + 4);
    __syncthreads();
    *(float4*)&As[lm * 32 + p0] = a0;
    *(float4*)&As[lm * 32 + p1] = a1;
    *(float4*)&Bs[lm * 32 + p0] = b0;
    *(float4*)&Bs[lm * 32 + p1] = b1;
    __syncthreads();
#pragma unroll
    for (int kq = 0; kq < 4; ++kq) {
      float4 av[8], bv[8];
#pragma unroll
      for (int i = 0; i < 8; ++i) {
        int m = row0 + i;
        av[i] = *(float4*)&As[m * 32 + ((kq * 4 + 4 * ((m >> 3) & 7)) & 31)];
      }
#pragma unroll
      for (int j = 0; j < 8; ++j) {
        int n = col0 + j;
        bv[j] = *(float4*)&Bs[n * 32 + ((kq * 4 + 4 * ((n >> 3) & 7)) & 31)];
      }
#pragma unroll
      for (int i = 0; i < 8; ++i)
#pragma unroll
        for (int j = 0; j < 8; ++j)
          acc[i][j] += av[i].x * bv[j].x + av[i].y * bv[j].y
                     + av[i].z * bv[j].z + av[i].w * bv[j].w;
    }
  }
  float bs[8];
#pragma unroll
  for (int j = 0; j < 8; ++j) {
    float v = bias1 ? bias1[nb + col0 + j] : 0.f;
    if (bias2) v += bias2[nb + col0 + j];
    bs[j] = v;
  }
  for (int i = 0; i < 8; ++i) {
    float* cp = Cout + (size_t)(mb + row0 + i) * Nn + nb + col0;
#pragma unroll
    for (int j = 0; j < 8; ++j) cp[j] = acc[i][j] + bs[j];
  }
}

// ---------- seq-partitioned encoder: 4-way k-split, 1024 threads ----------
__global__ __launch_bounds__(1024) void k_encoder_s(
    const float* __restrict__ wenc, const float* __restrict__ xpreF,
    const float* __restrict__ xpreB, const float* __restrict__ Vh0,
    const float* __restrict__ Vc0, float* __restrict__ encout,
    float* __restrict__ hT_out, float* __restrict__ cT_out) {
  __shared__ float hs[4][256];          // 4 KB
  __shared__ float pacc[3][16][256];    // 48 KB partials from kq=1..3
  int bid = blockIdx.x;
  int dir = bid >> 6;
  int s0 = (bid & 63) * 4;
  int tid = threadIdx.x;
  int j = tid & 255, kq = tid >> 8;
  float c[4];
  if (kq == 0) {
    float h0 = Vh0[dir * 256 + j];
    float c0v = Vc0[dir * 256 + j];
#pragma unroll
    for (int s = 0; s < 4; ++s) { hs[s][j] = h0; c[s] = c0v; }
  }
  __syncthreads();
  const float* wp = wenc + (size_t)dir * 262144 + (size_t)(kq * 64) * 1024 + (size_t)j * 4;
  const float* xbase = dir ? xpreB : xpreF;
  for (int t = 0; t < 64; ++t) {
    int w = dir ? (63 - t) : t;
    float acc[4][4];
#pragma unroll
    for (int s = 0; s < 4; ++s)
#pragma unroll
      for (int g = 0; g < 4; ++g) acc[s][g] = 0.f;
#pragma unroll 8
    for (int k = 0; k < 64; ++k) {
      float4 w4 = *(const float4*)(wp + (size_t)k * 1024);
      int kk = kq * 64 + k;
      float h0k = hs[0][kk], h1k = hs[1][kk], h2k = hs[2][kk], h3k = hs[3][kk];
      acc[0][0] += w4.x * h0k; acc[0][1] += w4.y * h0k; acc[0][2] += w4.z * h0k; acc[0][3] += w4.w * h0k;
      acc[1][0] += w4.x * h1k; acc[1][1] += w4.y * h1k; acc[1][2] += w4.z * h1k; acc[1][3] += w4.w * h1k;
      acc[2][0] += w4.x * h2k; acc[2][1] += w4.y * h2k; acc[2][2] += w4.z * h2k; acc[2][3] += w4.w * h2k;
      acc[3][0] += w4.x * h3k; acc[3][1] += w4.y * h3k; acc[3][2] += w4.z * h3k; acc[3][3] += w4.w * h3k;
    }
    if (kq > 0) {
#pragma unroll
      for (int s = 0; s < 4; ++s)
#pragma unroll
        for (int g = 0; g < 4; ++g)
          pacc[kq - 1][s * 4 + g][j] = acc[s][g];
    }
    __syncthreads();
    if (kq == 0) {
#pragma unroll
      for (int s = 0; s < 4; ++s) {
        int n = s0 + s;
        const float* xp = xbase + ((size_t)w * NSEQ + n) * GEH;
        float g4[4];
#pragma unroll
        for (int g = 0; g < 4; ++g)
          g4[g] = acc[s][g] + pacc[0][s * 4 + g][j] + pacc[1][s * 4 + g][j]
                + pacc[2][s * 4 + g][j] + xp[g * 256 + j];
        float cn = sigf(g4[1]) * c[s] + sigf(g4[0]) * tanhfast(g4[2]);
        c[s] = cn;
        float hn = sigf(g4[3]) * tanhfast(cn);
        hs[s][j] = hn;
        encout[((size_t)n * NW + w) * (2 * EH) + dir * EH + j] = hn;
      }
    }
    __syncthreads();
  }
  if (kq == 0) {
#pragma unroll
    for (int s = 0; s < 4; ++s) {
      int n = s0 + s;
      hT_out[((size_t)(dir * NSEQ + n)) * EH + j] = hs[s][j];
      cT_out[((size_t)(dir * NSEQ + n)) * EH + j] = c[s];
    }
  }
}

__global__ void k_conv(const float* __restrict__ hA, const float* __restrict__ cE,
                       const float* __restrict__ enc, float* __restrict__ cdec,
                       float* __restrict__ okT, float* __restrict__ ctx0) {
  int b = blockIdx.x, tid = threadIdx.x;
  for (int d = tid; d < 512; d += 256) {
    float s = 0.f;
    for (int p = 0; p < 1024; ++p) s += enc[((size_t)b * 1024 + p) * 512 + d];
    ctx0[(size_t)b * 512 + d] = s * (1.f / 1024.f);
    int dir = d >> 8, u = d & 255;
    float sh = 0.f, sc_ = 0.f;
    for (int hh = 0; hh < 16; ++hh) {
      size_t idx = ((size_t)(dir * NSEQ + b * 16 + hh)) * EH + u;
      sh += hA[idx]; sc_ += cE[idx];
    }
    cdec[(size_t)b * 512 + d] = sc_ * (1.f / 16.f);
    okT[(size_t)(256 + d) * 16 + b] = sh * (1.f / 16.f);
  }
}

// ---------- O0 + lin_h(h0) ----------
__global__ void k_O0v2(const float* __restrict__ okT, const float* __restrict__ ctx0,
                       const float* __restrict__ wcT, const float* __restrict__ wcb,
                       const float* __restrict__ whT, const float* __restrict__ whb,
                       float* __restrict__ okT_o, float* __restrict__ linh) {
  int b = blockIdx.x, tid = threadIdx.x;
  float a = wcb[tid];
  for (int k = 0; k < 512; ++k)
    a += okT[(size_t)(256 + k) * 16 + b] * wcT[(size_t)k * 256 + tid];
  const float* cb = ctx0 + (size_t)b * 512;
  for (int k = 0; k < 512; ++k)
    a += cb[k] * wcT[(size_t)(512 + k) * 256 + tid];
  okT_o[(size_t)tid * 16 + b] = tanhfast(a);
  for (int d = tid; d < 512; d += 256) {
    float v = whb[d];
    for (int k = 0; k < 512; ++k)
      v += okT[(size_t)(256 + k) * 16 + b] * whT[(size_t)k * 512 + d];
    linh[(size_t)b * 512 + d] = v;
  }
}

// ---------- embedding projection, tiled: block = 256 g x 32 tb ----------
__global__ __launch_bounds__(256) void k_embproj(
    const int* __restrict__ formulas, const float* __restrict__ emb,
    const float* __restrict__ wdT, const float* __restrict__ b1,
    const float* __restrict__ b2, float* __restrict__ ep) {
  __shared__ float se[32][NE];
  int gc = blockIdx.x, tc = blockIdx.y;
  int tid = threadIdx.x;
  int g = gc * 256 + tid;
  for (int i = tid; i < 32 * NE; i += 256) {
    int ti = i / NE, k = i - ti * NE;
    int tb = tc * 32 + ti;
    int b = tb & 15, t = tb >> 4;
    int tok = formulas[b * NT + t];
    se[ti][k] = emb[(size_t)tok * NE + k];
  }
  __syncthreads();
  float acc[32];
  float bias = b1[g] + b2[g];
#pragma unroll
  for (int i = 0; i < 32; ++i) acc[i] = bias;
  for (int k = 0; k < NE; ++k) {
    float w = wdT[(size_t)k * GDH + g];
#pragma unroll
    for (int i = 0; i < 32; ++i) acc[i] += se[i][k] * w;
  }
#pragma unroll
  for (int i = 0; i < 32; ++i)
    ep[(size_t)(tc * 32 + i) * GDH + g] = acc[i];
}

// ---------- logits helper (exp + per-chunk sums) ----------
__device__ __forceinline__ void logits_block(
    int vc, int lane, int wq, const float* __restrict__ okT,
    const float* __restrict__ woutT, const float* __restrict__ woutb,
    float* __restrict__ ev, float* __restrict__ evp) {
  int v = vc * 64 + lane;
  bool valid = v < NV;
  int vl = valid ? v : (NV - 1);
  float acc[4] = {0.f, 0.f, 0.f, 0.f};
  for (int k = 0; k < 256; ++k) {
    float w = woutT[(size_t)k * NV + vl];
    float4 o4 = *(const float4*)&okT[(size_t)k * 16 + wq * 4];
    acc[0] += w * o4.x; acc[1] += w * o4.y; acc[2] += w * o4.z; acc[3] += w * o4.w;
  }
  float bs = woutb[vl];
#pragma unroll
  for (int i = 0; i < 4; ++i) {
    float e = valid ? __expf(acc[i] + bs) : 0.f;
    if (valid) ev[(size_t)(wq * 4 + i) * NV + v] = e;
    float s = e;
#pragma unroll
    for (int m = 1; m < 64; m <<= 1) s += __shfl_xor(s, m, 64);
    if (lane == 0) evp[(wq * 4 + i) * 16 + vc] = s;
  }
}

__device__ __forceinline__ void norm_block(
    int b, int tid, const float* __restrict__ ev, const float* __restrict__ evp,
    float* __restrict__ outp, int t) {
  float tot = 0.f;
#pragma unroll
  for (int i = 0; i < 10; ++i) tot += evp[b * 16 + i];
  float r = __builtin_amdgcn_rcpf(tot);
  float* orow = outp + ((size_t)b * NT + t) * NV;
  orow[tid] = ev[b * NV + tid] * r;
  orow[tid + 256] = ev[b * NV + tid + 256] * r;
  if (tid < 88) orow[tid + 512] = ev[b * NV + tid + 512] * r;
}

// ---------- decoder K1: fused attention (512) | gates (48) | logits (10) ----------
// attention: one pass per position — score then immediate context accumulate;
// nontemporal loads keep the 67 MB/step stream out of L2 (weights stay hot).
__global__ __launch_bounds__(256) void k_dec1(
    const float* __restrict__ okT, const float* __restrict__ wdT,
    const float* __restrict__ woutT, const float* __restrict__ woutb,
    const float* __restrict__ linh, const float* __restrict__ beta,
    const float* __restrict__ wvenc, const float* __restrict__ enc,
    float* __restrict__ gpart, float* __restrict__ ctxp,
    float* __restrict__ spart, float* __restrict__ ev, float* __restrict__ evp,
    int t) {
  __shared__ float sscore[32];
  __shared__ float cpart[4][512];
  int bid = blockIdx.x, tid = threadIdx.x;
  int lane = tid & 63, wq = tid >> 6;

  if (bid < 512) {
    // attention tile: b = bid>>5, pc2 = bid&31 (32 positions); 4 waves x 8 pos
    int b = bid >> 5, pc2 = bid & 31;
    int d0 = lane * 8;
    float lh[8], bt[8];
    const float* lp = linh + (size_t)b * 512 + d0;
#pragma unroll
    for (int jj = 0; jj < 8; ++jj) { lh[jj] = lp[jj]; bt[jj] = beta[d0 + jj]; }
    float c8[8] = {0.f, 0.f, 0.f, 0.f, 0.f, 0.f, 0.f, 0.f};
#pragma unroll
    for (int pi = 0; pi < 8; ++pi) {
      int p = pc2 * 32 + wq * 8 + pi;
      const float* wvp = wvenc + ((size_t)(b * 1024 + p)) * 512 + d0;
      const float* erp = enc + ((size_t)(b * 1024 + p)) * 512 + d0;
      f32x4 wv0 = __builtin_nontemporal_load((const f32x4*)wvp);
      f32x4 wv1 = __builtin_nontemporal_load((const f32x4*)(wvp + 4));
      f32x4 e0 = __builtin_nontemporal_load((const f32x4*)erp);
      f32x4 e1 = __builtin_nontemporal_load((const f32x4*)(erp + 4));
      float e = bt[0] * tanhfast(lh[0] + wv0.x) + bt[1] * tanhfast(lh[1] + wv0.y)
              + bt[2] * tanhfast(lh[2] + wv0.z) + bt[3] * tanhfast(lh[3] + wv0.w)
              + bt[4] * tanhfast(lh[4] + wv1.x) + bt[5] * tanhfast(lh[5] + wv1.y)
              + bt[6] * tanhfast(lh[6] + wv1.z) + bt[7] * tanhfast(lh[7] + wv1.w);
#pragma unroll
      for (int m = 1; m < 64; m <<= 1) e += __shfl_xor(e, m, 64);
      float s = __expf(e);   // |e|<=5.2, safe without max-sub
      if (lane == 0) sscore[wq * 8 + pi] = s;
      c8[0] += s * e0.x; c8[1] += s * e0.y; c8[2] += s * e0.z; c8[3] += s * e0.w;
      c8[4] += s * e1.x; c8[5] += s * e1.y; c8[6] += s * e1.z; c8[7] += s * e1.w;
    }
#pragma unroll
    for (int jj = 0; jj < 8; ++jj) cpart[wq][d0 + jj] = c8[jj];
    __syncthreads();
    {
      int d = tid * 2;
      float r0 = cpart[0][d] + cpart[1][d] + cpart[2][d] + cpart[3][d];
      float r1 = cpart[0][d + 1] + cpart[1][d + 1] + cpart[2][d + 1] + cpart[3][d + 1];
      *(float2*)&ctxp[((size_t)(b * 32 + pc2)) * 512 + d] = make_float2(r0, r1);
    }
    if (tid == 0) {
      float s = 0.f;
#pragma unroll
      for (int p = 0; p < 32; ++p) s += sscore[p];
      spart[b * 32 + pc2] = s;
    }
  } else if (bid < 560) {
    // gates: oc = idx/6 (8 o-chunks of 256), kc = idx%6 (6 k-chunks of 128)
    int idx = bid - 512;
    int oc = idx / 6, kc = idx - oc * 6;
    int o = oc * 256 + tid, k0 = kc * 128;
    const float* wp = wdT + (size_t)(80 + k0) * GDH + o;
    const float* sp = okT + (size_t)k0 * 16;
    float acc[16];
#pragma unroll
    for (int i = 0; i < 16; ++i) acc[i] = 0.f;
    for (int kk = 0; kk < 128; ++kk) {
      float w = wp[(size_t)kk * GDH];
#pragma unroll
      for (int bb = 0; bb < 16; ++bb) acc[bb] += sp[kk * 16 + bb] * w;
    }
#pragma unroll
    for (int bb = 0; bb < 16; ++bb)
      gpart[((size_t)(kc * 16 + bb)) * GDH + o] = acc[bb];
  } else {
    if (t > 0) logits_block(bid - 560, lane, wq, okT, woutT, woutb, ev, evp);
  }
}

// ---------- decoder K2: reduce+cell+O_t+lin_h (64 blocks) | norm (16) ----------
__global__ __launch_bounds__(256) void k_dec2(
    const float* __restrict__ gpart, const float* __restrict__ ep,
    const float* __restrict__ ctxp, const float* __restrict__ spart,
    const float* __restrict__ wcT, const float* __restrict__ wcb,
    const float* __restrict__ whT, const float* __restrict__ whb,
    const float* __restrict__ ev, const float* __restrict__ evp,
    float* __restrict__ cdecA, float* __restrict__ cdecB,
    float* __restrict__ okT, float* __restrict__ linh,
    float* __restrict__ outp, int t) {
  __shared__ float smem[1280];
  int bid = blockIdx.x, tid = threadIdx.x;
  if (bid < 64) {
    int b = bid >> 2, q = bid & 3;
    const float* cold = (t & 1) ? cdecB : cdecA;
    float* cnew = (t & 1) ? cdecA : cdecB;
    float Ssum = 0.f;
#pragma unroll
    for (int pc = 0; pc < 32; ++pc) Ssum += spart[b * 32 + pc];
    float rS = __builtin_amdgcn_rcpf(Ssum);
    {
      int d = tid * 2;
      float s0 = 0.f, s1 = 0.f;
#pragma unroll 4
      for (int pc = 0; pc < 32; ++pc) {
        float2 c2 = *(const float2*)&ctxp[((size_t)(b * 32 + pc)) * 512 + d];
        s0 += c2.x; s1 += c2.y;
      }
      smem[512 + d] = s0 * rS;
      smem[512 + d + 1] = s1 * rS;
    }
#pragma unroll
    for (int half = 0; half < 2; ++half) {
      int j = half * 256 + tid;
      float g4[4];
#pragma unroll
      for (int gi = 0; gi < 4; ++gi) {
        float v = ep[((size_t)(t * 16 + b)) * GDH + gi * 512 + j];
#pragma unroll
        for (int kc = 0; kc < 6; ++kc)
          v += gpart[((size_t)(kc * 16 + b)) * GDH + gi * 512 + j];
        g4[gi] = v;
      }
      size_t ci = (size_t)b * 512 + j;
      float cn = sigf(g4[1]) * cold[ci] + sigf(g4[0]) * tanhfast(g4[2]);
      cnew[ci] = cn;
      float hn = sigf(g4[3]) * tanhfast(cn);
      smem[j] = hn;
      okT[(size_t)(256 + j) * 16 + b] = hn;
    }
    __syncthreads();
    // O_t slice: outputs q*64 .. q*64+63, k over [h;ctx]=smem[0..1023]
    {
      int ol = tid & 63, kq = tid >> 6;
      int o = q * 64 + ol;
      float a = 0.f;
      const float* wp = wcT + (size_t)(kq * 256) * 256 + o;
      const float* sp = smem + kq * 256;
      for (int k = 0; k < 256; ++k) a += wp[(size_t)k * 256] * sp[k];
      smem[1024 + kq * 64 + ol] = a;
    }
    __syncthreads();
    if (tid < 64) {
      float s = smem[1024 + tid] + smem[1088 + tid] + smem[1152 + tid] + smem[1216 + tid];
      int o = q * 64 + tid;
      okT[(size_t)o * 16 + b] = tanhfast(s + wcb[o]);
    }
    __syncthreads();
    // lin_h slice: outputs q*128 .. q*128+127, k over h=smem[0..511]
    {
      int o2 = tid & 127, kh = tid >> 7;
      int o = q * 128 + o2;
      float a = 0.f;
      const float* wp = whT + (size_t)(kh * 256) * 512 + o;
      const float* sp = smem + kh * 256;
      for (int k = 0; k < 256; ++k) a += wp[(size_t)k * 512] * sp[k];
      smem[1024 + kh * 128 + o2] = a;
    }
    __syncthreads();
    if (tid < 128) {
      int o = q * 128 + tid;
      float s = smem[1024 + tid] + smem[1152 + tid];
      linh[(size_t)b * 512 + o] = s + whb[o];
    }
  } else {
    if (t > 0) norm_block(bid - 64, tid, ev, evp, outp, t - 1);
  }
}

// ---------- tail: logits for t=127 ----------
__global__ __launch_bounds__(256) void k_log_tail(
    const float* __restrict__ okT, const float* __restrict__ woutT,
    const float* __restrict__ woutb, float* __restrict__ ev, float* __restrict__ evp) {
  int lane = threadIdx.x & 63, wq = threadIdx.x >> 6;
  logits_block(blockIdx.x, lane, wq, okT, woutT, woutb, ev, evp);
}

__global__ void k_norm(const float* __restrict__ ev, const float* __restrict__ evp,
                       float* __restrict__ outp, int t) {
  norm_block(blockIdx.x, threadIdx.x, ev, evp, outp, t);
}

__global__ void k_argmax(const float* __restrict__ outp, float* __restrict__ tgt) {
  int bt = blockIdx.x;
  int lane = threadIdx.x;
  const float* row = outp + (size_t)bt * NV;
  float bv = -1.f;
  int bi = 0;
  for (int v = lane; v < NV; v += 64) {
    float x = row[v];
    if (x > bv) { bv = x; bi = v; }
  }
#pragma unroll
  for (int m = 1; m < 64; m <<= 1) {
    float ov = __shfl_xor(bv, m, 64);
    int oi = __shfl_xor(bi, m, 64);
    if (ov > bv || (ov == bv && oi < bi)) { bv = ov; bi = oi; }
  }
  if (lane == 0) tgt[bt] = (float)bi;
}

extern "C" void kernel_launch(void* const* d_in, const int* in_sizes, int n_in,
                              void* d_out, int out_size, void* d_ws, size_t ws_size,
                              hipStream_t stream) {
  (void)in_sizes; (void)n_in; (void)out_size;
  if (ws_size < WS_FLOATS * sizeof(float)) return;

  const float* feat     = (const float*)d_in[0];
  const int*   formulas = (const int*)d_in[1];
  const float* Wih_f    = (const float*)d_in[2];
  const float* Whh_f    = (const float*)d_in[3];
  const float* bih_f    = (const float*)d_in[4];
  const float* bhh_f    = (const float*)d_in[5];
  const float* Wih_b    = (const float*)d_in[6];
  const float* Whh_b    = (const float*)d_in[7];
  const float* bih_b    = (const float*)d_in[8];
  const float* bhh_b    = (const float*)d_in[9];
  const float* emb      = (const float*)d_in[10];
  const float* Wc_w     = (const float*)d_in[11];
  const float* Wc_b     = (const float*)d_in[12];
  const float* Wout_w   = (const float*)d_in[13];
  const float* Wout_b   = (const float*)d_in[14];
  const float* Vh0      = (const float*)d_in[15];
  const float* Vc0      = (const float*)d_in[16];
  const float* beta     = (const float*)d_in[17];
  const float* Wh_w     = (const float*)d_in[18];
  const float* Wh_b     = (const float*)d_in[19];
  const float* Wv_w     = (const float*)d_in[20];
  const float* Wv_b     = (const float*)d_in[21];
  const float* Wdec_ih  = (const float*)d_in[22];
  const float* Wdec_hh  = (const float*)d_in[23];
  const float* bdec_ih  = (const float*)d_in[24];
  const float* bdec_hh  = (const float*)d_in[25];

  float* ws = (float*)d_ws;
  float* xpreF  = ws + OFF_XPRE_F;
  float* xpreB  = ws + OFF_XPRE_B;
  float* xt     = ws + OFF_XT;
  float* encout = ws + OFF_ENC;
  float* wenc   = ws + OFF_WENC;
  float* wdT    = ws + OFF_WDT;
  float* whT    = ws + OFF_WHT;
  float* wcT    = ws + OFF_WCT;
  float* woutT  = ws + OFF_WOUTT;
  float* hA     = ws + OFF_HA;
  float* cenc   = ws + OFF_CENC;
  float* cdecA  = ws + OFF_CDEC;
  float* ctx0   = ws + OFF_CTX0;
  float* okT    = ws + OFF_OKT;
  // decoder scratch aliased into xpreB (free after encoder)
  float* gpart  = xpreB;                 // 6*16*2048 = 196608
  float* ctxp   = gpart + 196608;        // 16*32*512 = 262144
  float* spart  = ctxp + 262144;         // 512
  float* ev     = spart + 512;           // 16*600 = 9600
  float* evp    = ev + 9600;             // 256
  float* linh   = evp + 256;             // 16*512 = 8192
  float* cdecB  = linh + 8192;           // 8192
  float* embproj = xpreF;                // alias (free after encoder)
  float* wvenc   = xt;                   // alias (free after input GEMMs)

  float* out_logits = (float*)d_out;
  float* out_tgt    = out_logits + (size_t)NB * NT * NV;

  // ---- prep ----
  k_transpose<<<(2048 * 336 + 255) / 256, 256, 0, stream>>>(wdT, Wdec_ih, 2048, 336);
  k_transpose<<<(2048 * 512 + 255) / 256, 256, 0, stream>>>(wdT + 336 * 2048, Wdec_hh, 2048, 512);
  k_transpose<<<(512 * 512 + 255) / 256, 256, 0, stream>>>(whT, Wh_w, 512, 512);
  k_transpose<<<(256 * 1024 + 255) / 256, 256, 0, stream>>>(wcT, Wc_w, 256, 1024);
  k_transpose<<<(600 * 256 + 255) / 256, 256, 0, stream>>>(woutT, Wout_w, 600, 256);
  k_prep_wenc<<<1024, 256, 0, stream>>>(wenc, Whh_f, 0);
  k_prep_wenc<<<1024, 256, 0, stream>>>(wenc, Whh_b, 1);
  k_buildXt<<<dim3(256, 8), 256, 0, stream>>>(xt, feat);
  k_gemm_nt<<<dim3(128, 8), 256, 0, stream>>>(xt, Wih_f, bih_f, bhh_f, xpreF, 16384, 1024, 512);
  k_gemm_nt<<<dim3(128, 8), 256, 0, stream>>>(xt, Wih_b, bih_b, bhh_b, xpreB, 16384, 1024, 512);

  // ---- encoder: one dispatch, zero grid sync ----
  k_encoder_s<<<128, 1024, 0, stream>>>(wenc, xpreF, xpreB, Vh0, Vc0, encout, hA, cenc);

  k_gemm_nt<<<dim3(128, 4), 256, 0, stream>>>(encout, Wv_w, Wv_b, nullptr, wvenc, 16384, 512, 512);
  k_conv<<<16, 256, 0, stream>>>(hA, cenc, encout, cdecA, okT, ctx0);
  k_O0v2<<<16, 256, 0, stream>>>(okT, ctx0, wcT, Wc_b, whT, Wh_b, okT, linh);
  k_embproj<<<dim3(8, 64), 256, 0, stream>>>(formulas, emb, wdT, bdec_ih, bdec_hh, embproj);

  // ---- decoder: 2 dispatches per step ----
  for (int t = 0; t < NT; ++t) {
    k_dec1<<<570, 256, 0, stream>>>(okT, wdT, woutT, Wout_b, linh, beta, wvenc, encout,
                                    gpart, ctxp, spart, ev, evp, t);
    k_dec2<<<80, 256, 0, stream>>>(gpart, embproj, ctxp, spart, wcT, Wc_b, whT, Wh_b,
                                   ev, evp, cdecA, cdecB, okT, linh, out_logits, t);
  }
  // ---- tail ----
  k_log_tail<<<10, 256, 0, stream>>>(okT, woutT, Wout_b, ev, evp);
  k_norm<<<16, 256, 0, stream>>>(ev, evp, out_logits, NT - 1);
  k_argmax<<<NB * NT, 64, 0, stream>>>(out_logits, out_tgt);
}